// Round 10
// baseline (1489.054 us; speedup 1.0000x reference)
//
#include <hip/hip_runtime.h>
#include <hip/hip_bf16.h>

#define NN 50000
#define NE 800000
#define FIN 80
#define H 128
#define H2 256
#define NG 64
#define NCLS 10
#define BN_EPS 1e-5f
#define NB 196    // ceil(NN/256)
#define LDK 40    // padded sA leading dim (shorts)
#define LDY 136   // padded sy-half leading dim (shorts)

typedef __attribute__((ext_vector_type(8))) short bf16x8;
typedef __attribute__((ext_vector_type(8))) unsigned short us8;
typedef __attribute__((ext_vector_type(4))) float f32x4;
typedef __attribute__((ext_vector_type(2))) float f32x2;

__device__ __forceinline__ unsigned short f2b(float f) {
    __hip_bfloat16 h = __float2bfloat16(f);   // RNE
    return *(unsigned short*)&h;
}
__device__ __forceinline__ float b2f(unsigned short u) {
    unsigned v = (unsigned)u << 16;
    return __uint_as_float(v);
}

// ---------------------------------------------------------------------------
// Weight prep: W[L][K][Nn] fp32 -> {hi,lo} bf16 planes, k-blocked:
// dst[l][ ((p*KB + kb)*Nn + n)*32 + kk ]
// ---------------------------------------------------------------------------
__global__ void wprep_all(const float* __restrict__ W1g, const float* __restrict__ W2g,
                          const float* __restrict__ W1f, const float* __restrict__ W2f,
                          unsigned short* __restrict__ wt)
{
    const int idx = blockIdx.x * 256 + threadIdx.x;   // grid = 2048*256
    const int m = idx >> 17;
    const int r = idx & 131071;
    const float* W;
    unsigned short* Wt;
    int K, Nn;
    if (m == 0)      { W = W1g; Wt = wt;              K = 128; Nn = 256; }
    else if (m == 1) { W = W2g; Wt = wt + 4 * 65536;  K = 256; Nn = 128; }
    else if (m == 2) { W = W1f; Wt = wt + 8 * 65536;  K = 128; Nn = 256; }
    else             { W = W2f; Wt = wt + 12 * 65536; K = 256; Nn = 128; }
    const int per = K * Nn;        // 32768
    const int l = r / per;
    const int rr = r - l * per;
    const int k = rr / Nn;
    const int n = rr - k * Nn;
    const float wv = W[r];
    const unsigned short hi = f2b(wv);
    const unsigned short lo = f2b(wv - b2f(hi));
    const int KB = K >> 5;
    const int kb = k >> 5, kk = k & 31;
    unsigned short* base = Wt + (size_t)l * 2 * per;
    base[((size_t)(0 * KB + kb) * Nn + n) * 32 + kk] = hi;
    base[((size_t)(1 * KB + kb) * Nn + n) * 32 + kk] = lo;
}

// ---------------------------------------------------------------------------
// Fused MLP pair, BM=128, 4 waves x 32 rows, wave-private tiles (no barriers
// in MFMA stages). N-SPLIT: stage1 runs in two 128-wide n-halves with the
// matching stage2 k-partial after each -> acc regs 192->128 AGPR, total
// ~220 <= 256 -> 2 waves/SIMD (R9 was ~272 -> 1 wave/SIMD or spills).
// Accumulation order k=0..127 then 128..255: bitwise identical to R9.
// A-fragments cached in 32 VGPRs across halves.
// ---------------------------------------------------------------------------
template<bool ZF>
__global__ __launch_bounds__(256, 2)
void gemm_pair(const void* __restrict__ Ap, const float* __restrict__ hres,
               const unsigned short* __restrict__ Wt1, const unsigned short* __restrict__ Wt2,
               const float* __restrict__ b1, const float* __restrict__ b2,
               const float* __restrict__ statsIn, const float* __restrict__ bng,
               const float* __restrict__ bnb, float* __restrict__ statsOut,
               float* __restrict__ Cout, float inv_n, int M)
{
    __shared__ unsigned short sA[ZF ? 128 : 1][LDK];  // 10.2 KB (ZF)
    __shared__ unsigned short sy[128][LDY];           // 34.8 KB (half-n y)
    __shared__ float sAB[128];
    __shared__ float sSH[128];

    const int tid = threadIdx.x;
    const int m0 = blockIdx.x * 128;
    const int lane = tid & 63;
    const int w = tid >> 6;
    const int fr = lane & 15;
    const int fq = (lane >> 4) * 8;
    const int crow4 = (lane >> 4) * 4;

    if (ZF) {
        // every wave computes all 128 entries redundantly (identical bits)
#pragma unroll
        for (int rep = 0; rep < 2; ++rep) {
            const int c = lane + rep * 64;
            float su = 0.f, qu = 0.f;
#pragma unroll
            for (int s = 0; s < 8; ++s) {
                su += statsIn[s * 256 + c];
                qu += statsIn[s * 256 + 128 + c];
            }
            const float mean = su * inv_n;
            const float var = qu * inv_n - mean * mean;
            const float a = bng[c] * rsqrtf(var + BN_EPS);
            sAB[c] = a;
            sSH[c] = fmaf(-mean, a, bnb[c]);
        }
    }

    const int arow = tid >> 1;          // wave w stages rows 32w..32w+31
    const int akh = (tid & 1) * 16;
    const int gm = m0 + arow;

    bf16x8 ac[2][4];                    // A-fragment cache across halves
    f32x4 acc2[2][8];
#pragma unroll
    for (int r = 0; r < 2; ++r)
#pragma unroll
        for (int c = 0; c < 8; ++c) acc2[r][c] = (f32x4)(0.f);

    for (int h2 = 0; h2 < 2; ++h2) {
        // ---------- stage 1 (half): y[:,h2*128..+128] ----------
        f32x4 acc1[2][8];
#pragma unroll
        for (int r = 0; r < 2; ++r)
#pragma unroll
            for (int c = 0; c < 8; ++c) acc1[r][c] = (f32x4)(0.f);

        for (int kb = 0; kb < 4; ++kb) {
            bf16x8 a0, a1;
            if (h2 == 0) {
                if (ZF) {
                    if (gm < M) {
                        const float* tf = (const float*)Ap + (size_t)gm * 128 + kb * 32 + akh;
                        const float* hf = hres + (size_t)gm * 128 + kb * 32 + akh;
                        const float4 t0 = *(const float4*)tf;
                        const float4 t1 = *(const float4*)(tf + 4);
                        const float4 t2 = *(const float4*)(tf + 8);
                        const float4 t3 = *(const float4*)(tf + 12);
                        const float4 h0 = *(const float4*)hf;
                        const float4 h1 = *(const float4*)(hf + 4);
                        const float4 h2v = *(const float4*)(hf + 8);
                        const float4 h3 = *(const float4*)(hf + 12);
                        const float tv[16] = {t0.x, t0.y, t0.z, t0.w, t1.x, t1.y, t1.z, t1.w,
                                              t2.x, t2.y, t2.z, t2.w, t3.x, t3.y, t3.z, t3.w};
                        const float hv[16] = {h0.x, h0.y, h0.z, h0.w, h1.x, h1.y, h1.z, h1.w,
                                              h2v.x, h2v.y, h2v.z, h2v.w, h3.x, h3.y, h3.z, h3.w};
                        us8 p0, p1;
#pragma unroll
                        for (int i = 0; i < 8; ++i) {
                            const int c = kb * 32 + akh + i;
                            const int c2 = c + 8;
                            p0[i] = f2b(fmaxf(fmaf(tv[i], sAB[c], sSH[c]), 0.f) + hv[i]);
                            p1[i] = f2b(fmaxf(fmaf(tv[8 + i], sAB[c2], sSH[c2]), 0.f) + hv[8 + i]);
                        }
                        *(us8*)&sA[arow][akh]     = p0;
                        *(us8*)&sA[arow][akh + 8] = p1;
                    } else {
                        *(float4*)&sA[arow][akh]     = make_float4(0.f, 0.f, 0.f, 0.f);
                        *(float4*)&sA[arow][akh + 8] = make_float4(0.f, 0.f, 0.f, 0.f);
                    }
                    // own wave's rows -> lgkm wait only, no barrier
                    a0 = *(const bf16x8*)&sA[w * 32 + fr][fq];
                    a1 = *(const bf16x8*)&sA[w * 32 + 16 + fr][fq];
                } else {
                    const unsigned short* z0 = (const unsigned short*)Ap +
                                               (size_t)(m0 + w * 32 + fr) * 128 + kb * 32 + fq;
                    const unsigned short* z1 = (const unsigned short*)Ap +
                                               (size_t)(m0 + w * 32 + 16 + fr) * 128 + kb * 32 + fq;
                    a0 = *(const bf16x8*)z0;
                    a1 = *(const bf16x8*)z1;
                }
                ac[0][kb] = a0;
                ac[1][kb] = a1;
            } else {
                a0 = ac[0][kb];
                a1 = ac[1][kb];
            }
#pragma unroll
            for (int nt = 0; nt < 8; ++nt) {
                const int nrow = h2 * 128 + nt * 16 + fr;
                const bf16x8 bh = *(const bf16x8*)&Wt1[((size_t)(kb) * 256 + nrow) * 32 + fq];
                const bf16x8 bl = *(const bf16x8*)&Wt1[((size_t)(4 + kb) * 256 + nrow) * 32 + fq];
                acc1[0][nt] = __builtin_amdgcn_mfma_f32_16x16x32_bf16(a0, bh, acc1[0][nt], 0, 0, 0);
                acc1[0][nt] = __builtin_amdgcn_mfma_f32_16x16x32_bf16(a0, bl, acc1[0][nt], 0, 0, 0);
                acc1[1][nt] = __builtin_amdgcn_mfma_f32_16x16x32_bf16(a1, bh, acc1[1][nt], 0, 0, 0);
                acc1[1][nt] = __builtin_amdgcn_mfma_f32_16x16x32_bf16(a1, bl, acc1[1][nt], 0, 0, 0);
            }
        }

        // y-half -> LDS (bias+relu+bf16), wave-private rows -> no barrier
#pragma unroll
        for (int nt = 0; nt < 8; ++nt) {
            const float bb = b1[h2 * 128 + nt * 16 + fr];
#pragma unroll
            for (int r = 0; r < 2; ++r) {
                const int row0 = w * 32 + r * 16 + crow4;
#pragma unroll
                for (int reg = 0; reg < 4; ++reg) {
                    const float o = fmaxf(acc1[r][nt][reg] + bb, 0.f);
                    sy[row0 + reg][nt * 16 + fr] = f2b(o);
                }
            }
        }

        // ---------- stage 2 partial: k = h2*128 .. +128 ----------
        for (int kb2 = 0; kb2 < 4; ++kb2) {
            const bf16x8 ya0 = *(const bf16x8*)&sy[w * 32 + fr][kb2 * 32 + fq];
            const bf16x8 ya1 = *(const bf16x8*)&sy[w * 32 + 16 + fr][kb2 * 32 + fq];
            const int kg = h2 * 4 + kb2;
#pragma unroll
            for (int ct = 0; ct < 8; ++ct) {
                const bf16x8 bh = *(const bf16x8*)&Wt2[((size_t)(kg) * 128 + ct * 16 + fr) * 32 + fq];
                const bf16x8 bl = *(const bf16x8*)&Wt2[((size_t)(8 + kg) * 128 + ct * 16 + fr) * 32 + fq];
                acc2[0][ct] = __builtin_amdgcn_mfma_f32_16x16x32_bf16(ya0, bh, acc2[0][ct], 0, 0, 0);
                acc2[0][ct] = __builtin_amdgcn_mfma_f32_16x16x32_bf16(ya0, bl, acc2[0][ct], 0, 0, 0);
                acc2[1][ct] = __builtin_amdgcn_mfma_f32_16x16x32_bf16(ya1, bh, acc2[1][ct], 0, 0, 0);
                acc2[1][ct] = __builtin_amdgcn_mfma_f32_16x16x32_bf16(ya1, bl, acc2[1][ct], 0, 0, 0);
            }
        }
        // sy reused next half: same wave rewrites its own rows after its own
        // reads -> race-free without barriers (in-wave lgkm ordering).
    }

    // ---------------- epilogue ----------------
    float s[8], q[8];
#pragma unroll
    for (int c = 0; c < 8; ++c) { s[c] = 0.f; q[c] = 0.f; }
#pragma unroll
    for (int r = 0; r < 2; ++r) {
        const int rbase = m0 + w * 32 + r * 16 + crow4;
#pragma unroll
        for (int ct = 0; ct < 8; ++ct) {
            const int gc = ct * 16 + fr;
            const float bb = b2[gc];
#pragma unroll
            for (int reg = 0; reg < 4; ++reg) {
                const int gr = rbase + reg;
                if (gr >= M) continue;
                float o = acc2[r][ct][reg] + bb;
                if (ZF) {
                    const float tv = ((const float*)Ap)[(size_t)gr * 128 + gc];
                    const float hv = hres[(size_t)gr * 128 + gc];
                    o += fmaxf(fmaf(tv, sAB[gc], sSH[gc]), 0.f) + hv;
                }
                s[ct] += o;
                q[ct] = fmaf(o, o, q[ct]);
                Cout[(size_t)gr * 128 + gc] = o;
            }
        }
    }

    // stats reduce -> 8 shadow slabs (red overlays sy -> 2 barriers, end only)
#pragma unroll
    for (int c = 0; c < 8; ++c) {
        s[c] += __shfl_xor(s[c], 32, 64); s[c] += __shfl_xor(s[c], 16, 64);
        q[c] += __shfl_xor(q[c], 32, 64); q[c] += __shfl_xor(q[c], 16, 64);
    }
    __syncthreads();
    float* red = (float*)sy;
    if (lane < 16) {
#pragma unroll
        for (int c = 0; c < 8; ++c) {
            red[w * 128 + c * 16 + lane]       = s[c];
            red[512 + w * 128 + c * 16 + lane] = q[c];
        }
    }
    __syncthreads();
    if (tid < 128) {
        const float ss = red[tid] + red[128 + tid] + red[256 + tid] + red[384 + tid];
        const float qq = red[512 + tid] + red[640 + tid] + red[768 + tid] + red[896 + tid];
        float* slab = statsOut + (blockIdx.x & 7) * 256;
        atomicAdd(&slab[tid], ss);
        atomicAdd(&slab[128 + tid], qq);
    }
}

// ---------------------------------------------------------------------------
// fp32 input-projection GEMM, reads x||pe directly.
// ---------------------------------------------------------------------------
__global__ __launch_bounds__(256, 4)
void inproj_kernel(const float* __restrict__ x, const float* __restrict__ pe,
                   const float* __restrict__ W, const float* __restrict__ bias,
                   float* __restrict__ C, unsigned short* __restrict__ Cb, int M)
{
    __shared__ float aT[16][129];
    __shared__ float wsh[16][129];

    const int tid = threadIdx.x;
    const int m0 = blockIdx.x * 128;
    const int rm = (tid >> 4) * 8;
    const int rn = (tid & 15) * 8;

    float acc[8][8];
#pragma unroll
    for (int i = 0; i < 8; ++i)
#pragma unroll
        for (int j = 0; j < 8; ++j) acc[i][j] = 0.f;

    const int lm = tid & 127;
    const int kq = (tid >> 7) * 8;
    const int wk = tid >> 4;
    const int wj = (tid & 15) * 8;

    for (int k0 = 0; k0 < FIN; k0 += 16) {
        {
            const int gm = m0 + lm;
            const int c = k0 + kq;
            if (gm < M) {
                const float* srcp = (c < 64) ? (x + (size_t)gm * 64 + c)
                                             : (pe + (size_t)gm * 16 + (c - 64));
                const float4 v0 = *(const float4*)srcp;
                const float4 v1 = *(const float4*)(srcp + 4);
                aT[kq + 0][lm] = v0.x; aT[kq + 1][lm] = v0.y;
                aT[kq + 2][lm] = v0.z; aT[kq + 3][lm] = v0.w;
                aT[kq + 4][lm] = v1.x; aT[kq + 5][lm] = v1.y;
                aT[kq + 6][lm] = v1.z; aT[kq + 7][lm] = v1.w;
            } else {
#pragma unroll
                for (int i = 0; i < 8; ++i) aT[kq + i][lm] = 0.f;
            }
        }
        {
#pragma unroll
            for (int j = 0; j < 8; ++j)
                wsh[wk][wj + j] = W[(size_t)(k0 + wk) * H + wj + j];
        }
        __syncthreads();
#pragma unroll
        for (int k = 0; k < 16; ++k) {
            const float av[8] = {aT[k][rm], aT[k][rm + 1], aT[k][rm + 2], aT[k][rm + 3],
                                 aT[k][rm + 4], aT[k][rm + 5], aT[k][rm + 6], aT[k][rm + 7]};
            const float bv[8] = {wsh[k][rn], wsh[k][rn + 1], wsh[k][rn + 2], wsh[k][rn + 3],
                                 wsh[k][rn + 4], wsh[k][rn + 5], wsh[k][rn + 6], wsh[k][rn + 7]};
#pragma unroll
            for (int i = 0; i < 8; ++i)
#pragma unroll
                for (int j = 0; j < 8; ++j)
                    acc[i][j] = fmaf(av[i], bv[j], acc[i][j]);
        }
        __syncthreads();
    }

    float bv[8];
#pragma unroll
    for (int j = 0; j < 8; ++j) bv[j] = bias[rn + j];
#pragma unroll
    for (int i = 0; i < 8; ++i) {
        const int gm = m0 + rm + i;
        if (gm >= M) continue;
        float o[8];
#pragma unroll
        for (int j = 0; j < 8; ++j) o[j] = fmaxf(acc[i][j] + bv[j], 0.f);
        *(float4*)&C[(size_t)gm * H + rn]     = make_float4(o[0], o[1], o[2], o[3]);
        *(float4*)&C[(size_t)gm * H + rn + 4] = make_float4(o[4], o[5], o[6], o[7]);
        us8 pk;
#pragma unroll
        for (int j = 0; j < 8; ++j) pk[j] = f2b(o[j]);
        *(us8*)&Cb[(size_t)gm * H + rn] = pk;
    }
}

// ---------------------------------------------------------------------------
// CSR build: histogram -> parallel scan -> index scatter -> coalesced gather
// ---------------------------------------------------------------------------
__global__ void hist_kernel(const int* __restrict__ ei, int* __restrict__ deg)
{
    const int e = blockIdx.x * 256 + threadIdx.x;
    if (e < NE) atomicAdd(&deg[ei[NE + e]], 1);
}

__global__ void bsum_kernel(const int* __restrict__ deg, int* __restrict__ bsum)
{
    const int tid = threadIdx.x;
    const int i = blockIdx.x * 256 + tid;
    int v = (i < NN) ? deg[i] : 0;
#pragma unroll
    for (int off = 32; off > 0; off >>= 1) v += __shfl_down(v, off, 64);
    __shared__ int ws[4];
    if ((tid & 63) == 0) ws[tid >> 6] = v;
    __syncthreads();
    if (tid == 0) bsum[blockIdx.x] = ws[0] + ws[1] + ws[2] + ws[3];
}

__global__ void bscan_kernel(int* __restrict__ bsum)
{
    __shared__ int sh[256];
    const int tid = threadIdx.x;
    sh[tid] = (tid < NB) ? bsum[tid] : 0;
    __syncthreads();
    for (int off = 1; off < 256; off <<= 1) {
        const int t = (tid >= off) ? sh[tid - off] : 0;
        __syncthreads();
        sh[tid] += t;
        __syncthreads();
    }
    if (tid < NB) bsum[tid] = (tid == 0) ? 0 : sh[tid - 1];
}

__global__ void bwrite_kernel(const int* __restrict__ deg, const int* __restrict__ boff,
                              int* __restrict__ rowptr, int* __restrict__ cursor)
{
    __shared__ int sh[256];
    const int tid = threadIdx.x;
    const int i = blockIdx.x * 256 + tid;
    const int v = (i < NN) ? deg[i] : 0;
    sh[tid] = v;
    __syncthreads();
    for (int off = 1; off < 256; off <<= 1) {
        const int t = (tid >= off) ? sh[tid - off] : 0;
        __syncthreads();
        sh[tid] += t;
        __syncthreads();
    }
    if (i < NN) {
        const int pos = boff[blockIdx.x] + sh[tid] - v;
        rowptr[i] = pos;
        cursor[i] = pos;
    }
    if (blockIdx.x == 0 && tid == 0) rowptr[NN] = NE;
}

__global__ void scat_idx(const int* __restrict__ ei, int* __restrict__ cursor,
                         int* __restrict__ src_s, int* __restrict__ perm)
{
    const int e = blockIdx.x * 256 + threadIdx.x;
    if (e >= NE) return;
    const int pos = atomicAdd(&cursor[ei[NE + e]], 1);
    src_s[pos] = ei[e];
    perm[pos] = e;
}

__global__ void gather_ea(const float* __restrict__ ea, const int* __restrict__ perm,
                          float* __restrict__ ea_s)
{
    const int idx = blockIdx.x * 256 + threadIdx.x;    // grid = NE*4/256
    const int pos = idx >> 2;
    const int qd = idx & 3;
    const int e = perm[pos];
    *(float4*)&ea_s[(size_t)pos * 16 + qd * 4] = *(const float4*)&ea[(size_t)e * 16 + qd * 4];
}

// ---------------------------------------------------------------------------
// Aggregation: z = (1+eps)*h + sum relu(h[src] + ea@We + be).
// TWO nodes per wave: both 16-deep gather batches issued before computing
// either -> ~32 outstanding loads/wave (latency hiding x2).
// ---------------------------------------------------------------------------
__global__ __launch_bounds__(256)
void agg_kernel(const float* __restrict__ h, const unsigned short* __restrict__ hb,
                const int* __restrict__ rowptr, const int* __restrict__ src_s,
                const float* __restrict__ ea_s, const float* __restrict__ We,
                const float* __restrict__ be, const float* __restrict__ eps, int l,
                unsigned short* __restrict__ zb)
{
    const int lane = threadIdx.x & 63;
    const int w = threadIdx.x >> 6;
    const int n0 = blockIdx.x * 8 + w * 2;
    if (n0 >= NN) return;
    const bool has1 = (n0 + 1 < NN);
    const int n1 = has1 ? (n0 + 1) : n0;

    f32x2 wv[16];
#pragma unroll
    for (int k = 0; k < 16; ++k)
        wv[k] = *(const f32x2*)&We[k * H + 2 * lane];
    const f32x2 bev = *(const f32x2*)&be[2 * lane];

    const int beg0 = __builtin_amdgcn_readfirstlane(rowptr[n0]);
    const int end0 = __builtin_amdgcn_readfirstlane(rowptr[n0 + 1]);
    const int beg1 = __builtin_amdgcn_readfirstlane(rowptr[n1]);
    const int end1 = __builtin_amdgcn_readfirstlane(rowptr[n1 + 1]);

    const float e1 = 1.0f + eps[l];
    f32x2 acc0 = (*(const f32x2*)&h[(size_t)n0 * H + 2 * lane]) * e1;
    f32x2 acc1 = (*(const f32x2*)&h[(size_t)n1 * H + 2 * lane]) * e1;

    int i0 = beg0, i1 = beg1;
    while (i0 < end0 || i1 < end1) {
        const int jn0 = min(16, end0 - i0);             // may be <= 0
        const int jn1 = has1 ? min(16, end1 - i1) : 0;  // may be <= 0
        int s0[16], s1[16];
#pragma unroll
        for (int j = 0; j < 16; ++j) {
            s0[j] = src_s[min(i0 + ((j < jn0) ? j : 0), NE - 1)];
            s1[j] = src_s[min(i1 + ((j < jn1) ? j : 0), NE - 1)];
        }
        unsigned hr0[16], hr1[16];
#pragma unroll
        for (int j = 0; j < 16; ++j)
            hr0[j] = *(const unsigned*)&hb[(size_t)s0[j] * H + 2 * lane];
#pragma unroll
        for (int j = 0; j < 16; ++j)
            hr1[j] = *(const unsigned*)&hb[(size_t)s1[j] * H + 2 * lane];

#pragma unroll
        for (int j = 0; j < 16; ++j) {
            if (j >= jn0) break;
            const float* ar = ea_s + (size_t)(i0 + j) * 16;
            f32x2 s2 = bev;
#pragma unroll
            for (int k = 0; k < 16; ++k)
                s2 = __builtin_elementwise_fma((f32x2)(ar[k]), wv[k], s2);
            f32x2 hv = {__uint_as_float(hr0[j] << 16),
                        __uint_as_float(hr0[j] & 0xffff0000u)};
            f32x2 m = hv + s2;
            m = __builtin_elementwise_max(m, (f32x2)(0.f));
            acc0 += m;
        }
#pragma unroll
        for (int j = 0; j < 16; ++j) {
            if (j >= jn1) break;
            const float* ar = ea_s + (size_t)(i1 + j) * 16;
            f32x2 s2 = bev;
#pragma unroll
            for (int k = 0; k < 16; ++k)
                s2 = __builtin_elementwise_fma((f32x2)(ar[k]), wv[k], s2);
            f32x2 hv = {__uint_as_float(hr1[j] << 16),
                        __uint_as_float(hr1[j] & 0xffff0000u)};
            f32x2 m = hv + s2;
            m = __builtin_elementwise_max(m, (f32x2)(0.f));
            acc1 += m;
        }
        if (jn0 > 0) i0 += jn0;
        if (jn1 > 0) i1 += jn1;
    }
    {
        const unsigned u = ((unsigned)f2b(acc0[1]) << 16) | (unsigned)f2b(acc0[0]);
        *(unsigned*)&zb[(size_t)n0 * H + 2 * lane] = u;
    }
    if (has1) {
        const unsigned u = ((unsigned)f2b(acc1[1]) << 16) | (unsigned)f2b(acc1[0]);
        *(unsigned*)&zb[(size_t)n1 * H + 2 * lane] = u;
    }
}

// ---------------------------------------------------------------------------
// bn_apply (8-shadow stats) / pool / readout
// ---------------------------------------------------------------------------
__global__ void bn_apply_kernel(const float* __restrict__ u, const float* __restrict__ st,
                                const float* __restrict__ g, const float* __restrict__ b,
                                float* __restrict__ h, unsigned short* __restrict__ hb,
                                float inv_n)
{
    const int i = blockIdx.x * 256 + threadIdx.x;
    const int c = i & (H - 1);
    float su = 0.f, qu = 0.f;
#pragma unroll
    for (int s = 0; s < 8; ++s) { su += st[s * 256 + c]; qu += st[s * 256 + 128 + c]; }
    const float mean = su * inv_n;
    const float var = qu * inv_n - mean * mean;
    const float a = g[c] * rsqrtf(var + BN_EPS);
    const float sh = fmaf(-mean, a, b[c]);
    const float v = fmaf(u[i], a, sh);
    h[i] = v;
    hb[i] = f2b(v);
}

__global__ void pool_kernel(const float* __restrict__ h, const int* __restrict__ batch,
                            float* __restrict__ pool, float* __restrict__ cnt, int n)
{
    const int c = threadIdx.x & (H - 1);
    const int half = threadIdx.x >> 7;
    const int r0 = blockIdx.x * 256 + half * 128;
    if (r0 >= n) return;
    const int rend = min(r0 + 128, n);
    int gprev = batch[r0];
    float acc = 0.f;
    int run = 0;
    for (int r = r0; r < rend; ++r) {
        const int g = batch[r];
        if (g != gprev) {
            atomicAdd(&pool[gprev * H + c], acc);
            if (c == 0) atomicAdd(&cnt[gprev], (float)run);
            acc = 0.f; run = 0; gprev = g;
        }
        acc += h[(size_t)r * H + c];
        run++;
    }
    atomicAdd(&pool[gprev * H + c], acc);
    if (c == 0) atomicAdd(&cnt[gprev], (float)run);
}

__global__ void readout_kernel(const float* __restrict__ pool, const float* __restrict__ cnt,
                               const float* __restrict__ Wr1, const float* __restrict__ br1,
                               const float* __restrict__ Wr2, const float* __restrict__ br2,
                               float* __restrict__ out)
{
    __shared__ float hg[H];
    __shared__ float r1[H];
    const int g = blockIdx.x;
    const int j = threadIdx.x;
    hg[j] = pool[g * H + j] / fmaxf(cnt[g], 1.0f);
    __syncthreads();
    float acc = br1[j];
    for (int k = 0; k < H; ++k) acc = fmaf(hg[k], Wr1[k * H + j], acc);
    r1[j] = fmaxf(acc, 0.f);
    __syncthreads();
    if (j < NCLS) {
        float o = br2[j];
        for (int k = 0; k < H; ++k) o = fmaf(r1[k], Wr2[k * NCLS + j], o);
        out[g * NCLS + j] = o;
    }
}

// ---------------------------------------------------------------------------
extern "C" void kernel_launch(void* const* d_in, const int* in_sizes, int n_in,
                              void* d_out, int out_size, void* d_ws, size_t ws_size,
                              hipStream_t stream)
{
    const float* x       = (const float*)d_in[0];
    const float* pe      = (const float*)d_in[1];
    const int*   ei      = (const int*)d_in[2];
    const float* ea      = (const float*)d_in[3];
    const int*   batch   = (const int*)d_in[4];
    const float* W_in    = (const float*)d_in[5];
    const float* b_in    = (const float*)d_in[6];
    const float* We_edge = (const float*)d_in[7];
    const float* be_edge = (const float*)d_in[8];
    const float* eps     = (const float*)d_in[9];
    const float* W1g     = (const float*)d_in[10];
    const float* b1g     = (const float*)d_in[11];
    const float* W2g     = (const float*)d_in[12];
    const float* b2g     = (const float*)d_in[13];
    const float* bn1g    = (const float*)d_in[14];
    const float* bn1b    = (const float*)d_in[15];
    const float* W1f     = (const float*)d_in[16];
    const float* b1f     = (const float*)d_in[17];
    const float* W2f     = (const float*)d_in[18];
    const float* b2f     = (const float*)d_in[19];
    const float* bn2g    = (const float*)d_in[20];
    const float* bn2b    = (const float*)d_in[21];
    const float* Wr1     = (const float*)d_in[22];
    const float* br1     = (const float*)d_in[23];
    const float* Wr2     = (const float*)d_in[24];
    const float* br2     = (const float*)d_in[25];
    float* out = (float*)d_out;

    const size_t NH = (size_t)NN * H;
    float* hbuf  = (float*)d_ws;                     // [NN,H] fp32
    float* tbuf  = hbuf + NH;                        // [NN,H] fp32 (t / u, in-place)
    unsigned short* zb = (unsigned short*)(tbuf + NH);  // [NN,H] bf16 z
    int*   perm  = (int*)(zb + NH);                  // [NE]
    // contiguous zero block: [deg NN][stats 16384][pool NG*H][cnt NG]
    int*   deg   = perm + NE;
    float* stats = (float*)(deg + NN);               // 4 layers x 2 slabs x 2048
    float* pool  = stats + 16384;                    // [NG,H]
    float* cnt   = pool + NG * H;                    // [NG]
    int*   rowptr = (int*)(cnt + NG);                // [NN+1]
    int*   cursor = rowptr + NN + 1;                 // [NN]
    int*   bsum   = cursor + NN;                     // [256]
    int*   src_s  = bsum + 256;                      // [NE]
    float* ea_s   = (float*)(src_s + NE);            // [NE,16]
    unsigned short* hb = (unsigned short*)(ea_s + (size_t)NE * 16);  // [NN,H] bf16
    unsigned short* wt = hb + NH;                    // 16 matrices x 2*K*N
    unsigned short* wt1g = wt;
    unsigned short* wt2g = wt + 4 * 65536;
    unsigned short* wt1f = wt + 8 * 65536;
    unsigned short* wt2f = wt + 12 * 65536;

    const dim3 blk(256);
    const dim3 ip_g((NN + 127) / 128, 1);
    const dim3 gp_g((NN + 127) / 128, 1);            // 391 blocks, BM=128
    const int ew_grid = (int)(NH / 256);
    const float inv_n = 1.0f / (float)NN;
    const size_t zero_bytes = (size_t)(NN + 16384 + NG * H + NG) * 4;

    // ---- weight prep ----
    wprep_all<<<2048, blk, 0, stream>>>(W1g, W2g, W1f, W2f, wt);

    // ---- zero-init + CSR build ----
    hipMemsetAsync(deg, 0, zero_bytes, stream);
    hist_kernel<<<(NE + 255) / 256, blk, 0, stream>>>(ei, deg);
    bsum_kernel<<<NB, blk, 0, stream>>>(deg, bsum);
    bscan_kernel<<<1, blk, 0, stream>>>(bsum);
    bwrite_kernel<<<NB, blk, 0, stream>>>(deg, bsum, rowptr, cursor);
    scat_idx<<<(NE + 255) / 256, blk, 0, stream>>>(ei, cursor, src_s, perm);
    gather_ea<<<(NE * 4) / 256, blk, 0, stream>>>(ea, perm, ea_s);

    // ---- input projection ----
    inproj_kernel<<<ip_g, blk, 0, stream>>>(x, pe, W_in, b_in, hbuf, hb, NN);

    for (int l = 0; l < 4; ++l) {
        float* s1 = stats + (size_t)l * 4096;
        float* s2 = s1 + 2048;

        // z (bf16) = (1+eps)*h + sum relu(h[src] + elin)
        agg_kernel<<<(NN + 7) / 8, blk, 0, stream>>>(hbuf, hb, rowptr, src_s, ea_s,
                                                     We_edge + (size_t)l * 16 * H,
                                                     be_edge + (size_t)l * H, eps, l, zb);

        // GIN pair: t = relu(z@W1g+b1g)@W2g + b2g   (+stats s1)
        gemm_pair<false><<<gp_g, blk, 0, stream>>>(
            zb, nullptr, wt1g + (size_t)l * 65536, wt2g + (size_t)l * 65536,
            b1g + (size_t)l * H2, b2g + (size_t)l * H,
            nullptr, nullptr, nullptr, s1, tbuf, inv_n, NN);

        // FFN pair: z = relu(bn1(t))+h; u = relu(z@W1f+b1f)@W2f + b2f + z  (+stats s2)
        gemm_pair<true><<<gp_g, blk, 0, stream>>>(
            tbuf, hbuf, wt1f + (size_t)l * 65536, wt2f + (size_t)l * 65536,
            b1f + (size_t)l * H2, b2f + (size_t)l * H,
            s1, bn1g + (size_t)l * H, bn1b + (size_t)l * H, s2, tbuf, inv_n, NN);

        // h = bn2(u)
        bn_apply_kernel<<<ew_grid, blk, 0, stream>>>(tbuf, s2, bn2g + (size_t)l * H,
                                                     bn2b + (size_t)l * H, hbuf, hb, inv_n);
    }

    pool_kernel<<<(NN + 255) / 256, blk, 0, stream>>>(hbuf, batch, pool, cnt, NN);
    readout_kernel<<<NG, H, 0, stream>>>(pool, cnt, Wr1, br1, Wr2, br2, out);
}

// Round 11
// 1142.728 us; speedup vs baseline: 1.3031x; 1.3031x over previous
//
#include <hip/hip_runtime.h>
#include <hip/hip_bf16.h>

#define NN 50000
#define NE 800000
#define FIN 80
#define H 128
#define H2 256
#define NG 64
#define NCLS 10
#define BN_EPS 1e-5f
#define NB 196    // ceil(NN/256)
#define LDK 40    // padded sA leading dim (shorts)
#define LDY 264   // padded sy leading dim (shorts)

typedef __attribute__((ext_vector_type(8))) short bf16x8;
typedef __attribute__((ext_vector_type(8))) unsigned short us8;
typedef __attribute__((ext_vector_type(4))) float f32x4;
typedef __attribute__((ext_vector_type(2))) float f32x2;

__device__ __forceinline__ unsigned short f2b(float f) {
    __hip_bfloat16 h = __float2bfloat16(f);   // RNE
    return *(unsigned short*)&h;
}
__device__ __forceinline__ float b2f(unsigned short u) {
    unsigned v = (unsigned)u << 16;
    return __uint_as_float(v);
}

// ---------------------------------------------------------------------------
// Weight prep: W[L][K][Nn] fp32 -> {hi,lo} bf16 planes, k-blocked:
// dst[l][ ((p*KB + kb)*Nn + n)*32 + kk ]
// ---------------------------------------------------------------------------
__global__ void wprep_all(const float* __restrict__ W1g, const float* __restrict__ W2g,
                          const float* __restrict__ W1f, const float* __restrict__ W2f,
                          unsigned short* __restrict__ wt)
{
    const int idx = blockIdx.x * 256 + threadIdx.x;   // grid = 2048*256
    const int m = idx >> 17;
    const int r = idx & 131071;
    const float* W;
    unsigned short* Wt;
    int K, Nn;
    if (m == 0)      { W = W1g; Wt = wt;              K = 128; Nn = 256; }
    else if (m == 1) { W = W2g; Wt = wt + 4 * 65536;  K = 256; Nn = 128; }
    else if (m == 2) { W = W1f; Wt = wt + 8 * 65536;  K = 128; Nn = 256; }
    else             { W = W2f; Wt = wt + 12 * 65536; K = 256; Nn = 128; }
    const int per = K * Nn;        // 32768
    const int l = r / per;
    const int rr = r - l * per;
    const int k = rr / Nn;
    const int n = rr - k * Nn;
    const float wv = W[r];
    const unsigned short hi = f2b(wv);
    const unsigned short lo = f2b(wv - b2f(hi));
    const int KB = K >> 5;
    const int kb = k >> 5, kk = k & 31;
    unsigned short* base = Wt + (size_t)l * 2 * per;
    base[((size_t)(0 * KB + kb) * Nn + n) * 32 + kk] = hi;
    base[((size_t)(1 * KB + kb) * Nn + n) * 32 + kk] = lo;
}

// ---------------------------------------------------------------------------
// Fused MLP pair, BM=128, 4 waves x 32 rows, wave-private tiles (no barriers
// in MFMA stages). Stage1 computed in two SEQUENTIAL n-halves: each half's
// acc1 (64 AGPR) dies at its sy-write before the next half / stage2 begin,
// so peak registers ~64 acc + ~80 arch (R9 held acc1[2][16]+acc2 = 192 AGPR
// live together -> 1 wave/SIMD, the latency-bound signature of R8's 21% occ).
// Stage2 is one full-k pass -> accumulation order bitwise identical to R9.
// GIN (ZF=false): A read directly from bf16 zb (L2-hot). FFN (ZF=true):
// staging computes z = relu(bn1(t))+h (recomputed per half, same bits);
// epilogue adds recomputed z as residual. statsOut -> 8 shadow slabs.
// ---------------------------------------------------------------------------
template<bool ZF>
__global__ __launch_bounds__(256, 2)
void gemm_pair(const void* __restrict__ Ap, const float* __restrict__ hres,
               const unsigned short* __restrict__ Wt1, const unsigned short* __restrict__ Wt2,
               const float* __restrict__ b1, const float* __restrict__ b2,
               const float* __restrict__ statsIn, const float* __restrict__ bng,
               const float* __restrict__ bnb, float* __restrict__ statsOut,
               float* __restrict__ Cout, float inv_n, int M)
{
    __shared__ unsigned short sA[ZF ? 128 : 1][LDK];  // 10.2 KB (ZF)
    __shared__ unsigned short sy[128][LDY];           // 67.6 KB
    __shared__ float sAB[128];
    __shared__ float sSH[128];

    const int tid = threadIdx.x;
    const int m0 = blockIdx.x * 128;
    const int lane = tid & 63;
    const int w = tid >> 6;
    const int fr = lane & 15;
    const int fq = (lane >> 4) * 8;
    const int crow4 = (lane >> 4) * 4;

    if (ZF) {
        // every wave computes all 128 entries redundantly (identical bits)
#pragma unroll
        for (int rep = 0; rep < 2; ++rep) {
            const int c = lane + rep * 64;
            float su = 0.f, qu = 0.f;
#pragma unroll
            for (int s = 0; s < 8; ++s) {
                su += statsIn[s * 256 + c];
                qu += statsIn[s * 256 + 128 + c];
            }
            const float mean = su * inv_n;
            const float var = qu * inv_n - mean * mean;
            const float a = bng[c] * rsqrtf(var + BN_EPS);
            sAB[c] = a;
            sSH[c] = fmaf(-mean, a, bnb[c]);
        }
    }

    const int arow = tid >> 1;          // wave w stages rows 32w..32w+31
    const int akh = (tid & 1) * 16;
    const int gm = m0 + arow;

    // ---------------- stage 1 in two sequential n-halves ----------------
#pragma unroll 1
    for (int hh = 0; hh < 2; ++hh) {
        f32x4 acc1[2][8];
#pragma unroll
        for (int r = 0; r < 2; ++r)
#pragma unroll
            for (int c = 0; c < 8; ++c) acc1[r][c] = (f32x4)(0.f);

        for (int kb = 0; kb < 4; ++kb) {
            bf16x8 a0, a1;
            if (ZF) {
                if (gm < M) {
                    const float* tf = (const float*)Ap + (size_t)gm * 128 + kb * 32 + akh;
                    const float* hf = hres + (size_t)gm * 128 + kb * 32 + akh;
                    const float4 t0 = *(const float4*)tf;
                    const float4 t1 = *(const float4*)(tf + 4);
                    const float4 t2 = *(const float4*)(tf + 8);
                    const float4 t3 = *(const float4*)(tf + 12);
                    const float4 h0 = *(const float4*)hf;
                    const float4 h1 = *(const float4*)(hf + 4);
                    const float4 h2v = *(const float4*)(hf + 8);
                    const float4 h3 = *(const float4*)(hf + 12);
                    const float tv[16] = {t0.x, t0.y, t0.z, t0.w, t1.x, t1.y, t1.z, t1.w,
                                          t2.x, t2.y, t2.z, t2.w, t3.x, t3.y, t3.z, t3.w};
                    const float hv[16] = {h0.x, h0.y, h0.z, h0.w, h1.x, h1.y, h1.z, h1.w,
                                          h2v.x, h2v.y, h2v.z, h2v.w, h3.x, h3.y, h3.z, h3.w};
                    us8 p0, p1;
#pragma unroll
                    for (int i = 0; i < 8; ++i) {
                        const int c = kb * 32 + akh + i;
                        const int c2 = c + 8;
                        p0[i] = f2b(fmaxf(fmaf(tv[i], sAB[c], sSH[c]), 0.f) + hv[i]);
                        p1[i] = f2b(fmaxf(fmaf(tv[8 + i], sAB[c2], sSH[c2]), 0.f) + hv[8 + i]);
                    }
                    *(us8*)&sA[arow][akh]     = p0;
                    *(us8*)&sA[arow][akh + 8] = p1;
                } else {
                    *(float4*)&sA[arow][akh]     = make_float4(0.f, 0.f, 0.f, 0.f);
                    *(float4*)&sA[arow][akh + 8] = make_float4(0.f, 0.f, 0.f, 0.f);
                }
                // own wave's rows -> lgkm wait only, no barrier
                a0 = *(const bf16x8*)&sA[w * 32 + fr][fq];
                a1 = *(const bf16x8*)&sA[w * 32 + 16 + fr][fq];
            } else {
                const unsigned short* z0 = (const unsigned short*)Ap +
                                           (size_t)(m0 + w * 32 + fr) * 128 + kb * 32 + fq;
                const unsigned short* z1 = (const unsigned short*)Ap +
                                           (size_t)(m0 + w * 32 + 16 + fr) * 128 + kb * 32 + fq;
                a0 = *(const bf16x8*)z0;
                a1 = *(const bf16x8*)z1;
            }
#pragma unroll
            for (int nt = 0; nt < 8; ++nt) {
                const int nrow = hh * 128 + nt * 16 + fr;
                const bf16x8 bh = *(const bf16x8*)&Wt1[((size_t)(kb) * 256 + nrow) * 32 + fq];
                const bf16x8 bl = *(const bf16x8*)&Wt1[((size_t)(4 + kb) * 256 + nrow) * 32 + fq];
                acc1[0][nt] = __builtin_amdgcn_mfma_f32_16x16x32_bf16(a0, bh, acc1[0][nt], 0, 0, 0);
                acc1[0][nt] = __builtin_amdgcn_mfma_f32_16x16x32_bf16(a0, bl, acc1[0][nt], 0, 0, 0);
                acc1[1][nt] = __builtin_amdgcn_mfma_f32_16x16x32_bf16(a1, bh, acc1[1][nt], 0, 0, 0);
                acc1[1][nt] = __builtin_amdgcn_mfma_f32_16x16x32_bf16(a1, bl, acc1[1][nt], 0, 0, 0);
            }
        }

        // y-half -> LDS (bias+relu+bf16), wave-private rows -> no barrier.
        // acc1 dies here -> registers free before next half / stage2.
#pragma unroll
        for (int nt = 0; nt < 8; ++nt) {
            const float bb = b1[hh * 128 + nt * 16 + fr];
#pragma unroll
            for (int r = 0; r < 2; ++r) {
                const int row0 = w * 32 + r * 16 + crow4;
#pragma unroll
                for (int reg = 0; reg < 4; ++reg) {
                    const float o = fmaxf(acc1[r][nt][reg] + bb, 0.f);
                    sy[row0 + reg][hh * 128 + nt * 16 + fr] = f2b(o);
                }
            }
        }
    }

    // ---------------- stage 2: C = y @ W2 + b2 (full k pass) ----------------
    f32x4 acc2[2][8];
#pragma unroll
    for (int r = 0; r < 2; ++r)
#pragma unroll
        for (int c = 0; c < 8; ++c) acc2[r][c] = (f32x4)(0.f);

    for (int kb = 0; kb < 8; ++kb) {
        const bf16x8 ya0 = *(const bf16x8*)&sy[w * 32 + fr][kb * 32 + fq];
        const bf16x8 ya1 = *(const bf16x8*)&sy[w * 32 + 16 + fr][kb * 32 + fq];
#pragma unroll
        for (int ct = 0; ct < 8; ++ct) {
            const bf16x8 bh = *(const bf16x8*)&Wt2[((size_t)(kb) * 128 + ct * 16 + fr) * 32 + fq];
            const bf16x8 bl = *(const bf16x8*)&Wt2[((size_t)(8 + kb) * 128 + ct * 16 + fr) * 32 + fq];
            acc2[0][ct] = __builtin_amdgcn_mfma_f32_16x16x32_bf16(ya0, bh, acc2[0][ct], 0, 0, 0);
            acc2[0][ct] = __builtin_amdgcn_mfma_f32_16x16x32_bf16(ya0, bl, acc2[0][ct], 0, 0, 0);
            acc2[1][ct] = __builtin_amdgcn_mfma_f32_16x16x32_bf16(ya1, bh, acc2[1][ct], 0, 0, 0);
            acc2[1][ct] = __builtin_amdgcn_mfma_f32_16x16x32_bf16(ya1, bl, acc2[1][ct], 0, 0, 0);
        }
    }

    // ---------------- epilogue ----------------
    float s[8], q[8];
#pragma unroll
    for (int c = 0; c < 8; ++c) { s[c] = 0.f; q[c] = 0.f; }
#pragma unroll
    for (int r = 0; r < 2; ++r) {
        const int rbase = m0 + w * 32 + r * 16 + crow4;
#pragma unroll
        for (int ct = 0; ct < 8; ++ct) {
            const int gc = ct * 16 + fr;
            const float bb = b2[gc];
#pragma unroll
            for (int reg = 0; reg < 4; ++reg) {
                const int gr = rbase + reg;
                if (gr >= M) continue;
                float o = acc2[r][ct][reg] + bb;
                if (ZF) {
                    const float tv = ((const float*)Ap)[(size_t)gr * 128 + gc];
                    const float hv = hres[(size_t)gr * 128 + gc];
                    o += fmaxf(fmaf(tv, sAB[gc], sSH[gc]), 0.f) + hv;
                }
                s[ct] += o;
                q[ct] = fmaf(o, o, q[ct]);
                Cout[(size_t)gr * 128 + gc] = o;
            }
        }
    }

    // stats reduce -> 8 shadow slabs (red overlays sy -> 2 barriers, end only)
#pragma unroll
    for (int c = 0; c < 8; ++c) {
        s[c] += __shfl_xor(s[c], 32, 64); s[c] += __shfl_xor(s[c], 16, 64);
        q[c] += __shfl_xor(q[c], 32, 64); q[c] += __shfl_xor(q[c], 16, 64);
    }
    __syncthreads();
    float* red = (float*)sy;
    if (lane < 16) {
#pragma unroll
        for (int c = 0; c < 8; ++c) {
            red[w * 128 + c * 16 + lane]       = s[c];
            red[512 + w * 128 + c * 16 + lane] = q[c];
        }
    }
    __syncthreads();
    if (tid < 128) {
        const float ss = red[tid] + red[128 + tid] + red[256 + tid] + red[384 + tid];
        const float qq = red[512 + tid] + red[640 + tid] + red[768 + tid] + red[896 + tid];
        float* slab = statsOut + (blockIdx.x & 7) * 256;
        atomicAdd(&slab[tid], ss);
        atomicAdd(&slab[128 + tid], qq);
    }
}

// ---------------------------------------------------------------------------
// fp32 input-projection GEMM, reads x||pe directly.
// ---------------------------------------------------------------------------
__global__ __launch_bounds__(256, 4)
void inproj_kernel(const float* __restrict__ x, const float* __restrict__ pe,
                   const float* __restrict__ W, const float* __restrict__ bias,
                   float* __restrict__ C, unsigned short* __restrict__ Cb, int M)
{
    __shared__ float aT[16][129];
    __shared__ float wsh[16][129];

    const int tid = threadIdx.x;
    const int m0 = blockIdx.x * 128;
    const int rm = (tid >> 4) * 8;
    const int rn = (tid & 15) * 8;

    float acc[8][8];
#pragma unroll
    for (int i = 0; i < 8; ++i)
#pragma unroll
        for (int j = 0; j < 8; ++j) acc[i][j] = 0.f;

    const int lm = tid & 127;
    const int kq = (tid >> 7) * 8;
    const int wk = tid >> 4;
    const int wj = (tid & 15) * 8;

    for (int k0 = 0; k0 < FIN; k0 += 16) {
        {
            const int gm = m0 + lm;
            const int c = k0 + kq;
            if (gm < M) {
                const float* srcp = (c < 64) ? (x + (size_t)gm * 64 + c)
                                             : (pe + (size_t)gm * 16 + (c - 64));
                const float4 v0 = *(const float4*)srcp;
                const float4 v1 = *(const float4*)(srcp + 4);
                aT[kq + 0][lm] = v0.x; aT[kq + 1][lm] = v0.y;
                aT[kq + 2][lm] = v0.z; aT[kq + 3][lm] = v0.w;
                aT[kq + 4][lm] = v1.x; aT[kq + 5][lm] = v1.y;
                aT[kq + 6][lm] = v1.z; aT[kq + 7][lm] = v1.w;
            } else {
#pragma unroll
                for (int i = 0; i < 8; ++i) aT[kq + i][lm] = 0.f;
            }
        }
        {
#pragma unroll
            for (int j = 0; j < 8; ++j)
                wsh[wk][wj + j] = W[(size_t)(k0 + wk) * H + wj + j];
        }
        __syncthreads();
#pragma unroll
        for (int k = 0; k < 16; ++k) {
            const float av[8] = {aT[k][rm], aT[k][rm + 1], aT[k][rm + 2], aT[k][rm + 3],
                                 aT[k][rm + 4], aT[k][rm + 5], aT[k][rm + 6], aT[k][rm + 7]};
            const float bv[8] = {wsh[k][rn], wsh[k][rn + 1], wsh[k][rn + 2], wsh[k][rn + 3],
                                 wsh[k][rn + 4], wsh[k][rn + 5], wsh[k][rn + 6], wsh[k][rn + 7]};
#pragma unroll
            for (int i = 0; i < 8; ++i)
#pragma unroll
                for (int j = 0; j < 8; ++j)
                    acc[i][j] = fmaf(av[i], bv[j], acc[i][j]);
        }
        __syncthreads();
    }

    float bv[8];
#pragma unroll
    for (int j = 0; j < 8; ++j) bv[j] = bias[rn + j];
#pragma unroll
    for (int i = 0; i < 8; ++i) {
        const int gm = m0 + rm + i;
        if (gm >= M) continue;
        float o[8];
#pragma unroll
        for (int j = 0; j < 8; ++j) o[j] = fmaxf(acc[i][j] + bv[j], 0.f);
        *(float4*)&C[(size_t)gm * H + rn]     = make_float4(o[0], o[1], o[2], o[3]);
        *(float4*)&C[(size_t)gm * H + rn + 4] = make_float4(o[4], o[5], o[6], o[7]);
        us8 pk;
#pragma unroll
        for (int j = 0; j < 8; ++j) pk[j] = f2b(o[j]);
        *(us8*)&Cb[(size_t)gm * H + rn] = pk;
    }
}

// ---------------------------------------------------------------------------
// CSR build: histogram -> parallel scan -> index scatter -> coalesced gather
// ---------------------------------------------------------------------------
__global__ void hist_kernel(const int* __restrict__ ei, int* __restrict__ deg)
{
    const int e = blockIdx.x * 256 + threadIdx.x;
    if (e < NE) atomicAdd(&deg[ei[NE + e]], 1);
}

__global__ void bsum_kernel(const int* __restrict__ deg, int* __restrict__ bsum)
{
    const int tid = threadIdx.x;
    const int i = blockIdx.x * 256 + tid;
    int v = (i < NN) ? deg[i] : 0;
#pragma unroll
    for (int off = 32; off > 0; off >>= 1) v += __shfl_down(v, off, 64);
    __shared__ int ws[4];
    if ((tid & 63) == 0) ws[tid >> 6] = v;
    __syncthreads();
    if (tid == 0) bsum[blockIdx.x] = ws[0] + ws[1] + ws[2] + ws[3];
}

__global__ void bscan_kernel(int* __restrict__ bsum)
{
    __shared__ int sh[256];
    const int tid = threadIdx.x;
    sh[tid] = (tid < NB) ? bsum[tid] : 0;
    __syncthreads();
    for (int off = 1; off < 256; off <<= 1) {
        const int t = (tid >= off) ? sh[tid - off] : 0;
        __syncthreads();
        sh[tid] += t;
        __syncthreads();
    }
    if (tid < NB) bsum[tid] = (tid == 0) ? 0 : sh[tid - 1];
}

__global__ void bwrite_kernel(const int* __restrict__ deg, const int* __restrict__ boff,
                              int* __restrict__ rowptr, int* __restrict__ cursor)
{
    __shared__ int sh[256];
    const int tid = threadIdx.x;
    const int i = blockIdx.x * 256 + tid;
    const int v = (i < NN) ? deg[i] : 0;
    sh[tid] = v;
    __syncthreads();
    for (int off = 1; off < 256; off <<= 1) {
        const int t = (tid >= off) ? sh[tid - off] : 0;
        __syncthreads();
        sh[tid] += t;
        __syncthreads();
    }
    if (i < NN) {
        const int pos = boff[blockIdx.x] + sh[tid] - v;
        rowptr[i] = pos;
        cursor[i] = pos;
    }
    if (blockIdx.x == 0 && tid == 0) rowptr[NN] = NE;
}

__global__ void scat_idx(const int* __restrict__ ei, int* __restrict__ cursor,
                         int* __restrict__ src_s, int* __restrict__ perm)
{
    const int e = blockIdx.x * 256 + threadIdx.x;
    if (e >= NE) return;
    const int pos = atomicAdd(&cursor[ei[NE + e]], 1);
    src_s[pos] = ei[e];
    perm[pos] = e;
}

__global__ void gather_ea(const float* __restrict__ ea, const int* __restrict__ perm,
                          float* __restrict__ ea_s)
{
    const int idx = blockIdx.x * 256 + threadIdx.x;    // grid = NE*4/256
    const int pos = idx >> 2;
    const int qd = idx & 3;
    const int e = perm[pos];
    *(float4*)&ea_s[(size_t)pos * 16 + qd * 4] = *(const float4*)&ea[(size_t)e * 16 + qd * 4];
}

// ---------------------------------------------------------------------------
// Aggregation (R9 exact form — proven 78.7 us): one wave/node, 16-deep
// gather pipeline, packed float2 math; writes z as bf16.
// ---------------------------------------------------------------------------
__global__ __launch_bounds__(256)
void agg_kernel(const float* __restrict__ h, const unsigned short* __restrict__ hb,
                const int* __restrict__ rowptr, const int* __restrict__ src_s,
                const float* __restrict__ ea_s, const float* __restrict__ We,
                const float* __restrict__ be, const float* __restrict__ eps, int l,
                unsigned short* __restrict__ zb)
{
    const int lane = threadIdx.x & 63;
    const int w = threadIdx.x >> 6;
    const int n = blockIdx.x * 4 + w;
    if (n >= NN) return;

    f32x2 wv[16];
#pragma unroll
    for (int k = 0; k < 16; ++k)
        wv[k] = *(const f32x2*)&We[k * H + 2 * lane];
    const f32x2 bev = *(const f32x2*)&be[2 * lane];

    const int beg = __builtin_amdgcn_readfirstlane(rowptr[n]);
    const int end = __builtin_amdgcn_readfirstlane(rowptr[n + 1]);

    const float e1 = 1.0f + eps[l];
    f32x2 acc = (*(const f32x2*)&h[(size_t)n * H + 2 * lane]) * e1;

    for (int i0 = beg; i0 < end; i0 += 16) {
        const int jn = min(16, end - i0);
        int srcs[16];
#pragma unroll
        for (int j = 0; j < 16; ++j)
            srcs[j] = src_s[(i0 + j < end) ? (i0 + j) : (end - 1)];
        unsigned hraw[16];
#pragma unroll
        for (int j = 0; j < 16; ++j)
            hraw[j] = *(const unsigned*)&hb[(size_t)srcs[j] * H + 2 * lane];
#pragma unroll
        for (int j = 0; j < 16; ++j) {
            if (j >= jn) break;
            const float* ar = ea_s + (size_t)(i0 + j) * 16;
            f32x2 s2 = bev;
#pragma unroll
            for (int k = 0; k < 16; ++k)
                s2 = __builtin_elementwise_fma((f32x2)(ar[k]), wv[k], s2);
            f32x2 hv = {__uint_as_float(hraw[j] << 16),
                        __uint_as_float(hraw[j] & 0xffff0000u)};
            f32x2 m = hv + s2;
            m = __builtin_elementwise_max(m, (f32x2)(0.f));
            acc += m;
        }
    }
    const unsigned u = ((unsigned)f2b(acc[1]) << 16) | (unsigned)f2b(acc[0]);
    *(unsigned*)&zb[(size_t)n * H + 2 * lane] = u;
}

// ---------------------------------------------------------------------------
// bn_apply (8-shadow stats) / pool / readout
// ---------------------------------------------------------------------------
__global__ void bn_apply_kernel(const float* __restrict__ u, const float* __restrict__ st,
                                const float* __restrict__ g, const float* __restrict__ b,
                                float* __restrict__ h, unsigned short* __restrict__ hb,
                                float inv_n)
{
    const int i = blockIdx.x * 256 + threadIdx.x;
    const int c = i & (H - 1);
    float su = 0.f, qu = 0.f;
#pragma unroll
    for (int s = 0; s < 8; ++s) { su += st[s * 256 + c]; qu += st[s * 256 + 128 + c]; }
    const float mean = su * inv_n;
    const float var = qu * inv_n - mean * mean;
    const float a = g[c] * rsqrtf(var + BN_EPS);
    const float sh = fmaf(-mean, a, b[c]);
    const float v = fmaf(u[i], a, sh);
    h[i] = v;
    hb[i] = f2b(v);
}

__global__ void pool_kernel(const float* __restrict__ h, const int* __restrict__ batch,
                            float* __restrict__ pool, float* __restrict__ cnt, int n)
{
    const int c = threadIdx.x & (H - 1);
    const int half = threadIdx.x >> 7;
    const int r0 = blockIdx.x * 256 + half * 128;
    if (r0 >= n) return;
    const int rend = min(r0 + 128, n);
    int gprev = batch[r0];
    float acc = 0.f;
    int run = 0;
    for (int r = r0; r < rend; ++r) {
        const int g = batch[r];
        if (g != gprev) {
            atomicAdd(&pool[gprev * H + c], acc);
            if (c == 0) atomicAdd(&cnt[gprev], (float)run);
            acc = 0.f; run = 0; gprev = g;
        }
        acc += h[(size_t)r * H + c];
        run++;
    }
    atomicAdd(&pool[gprev * H + c], acc);
    if (c == 0) atomicAdd(&cnt[gprev], (float)run);
}

__global__ void readout_kernel(const float* __restrict__ pool, const float* __restrict__ cnt,
                               const float* __restrict__ Wr1, const float* __restrict__ br1,
                               const float* __restrict__ Wr2, const float* __restrict__ br2,
                               float* __restrict__ out)
{
    __shared__ float hg[H];
    __shared__ float r1[H];
    const int g = blockIdx.x;
    const int j = threadIdx.x;
    hg[j] = pool[g * H + j] / fmaxf(cnt[g], 1.0f);
    __syncthreads();
    float acc = br1[j];
    for (int k = 0; k < H; ++k) acc = fmaf(hg[k], Wr1[k * H + j], acc);
    r1[j] = fmaxf(acc, 0.f);
    __syncthreads();
    if (j < NCLS) {
        float o = br2[j];
        for (int k = 0; k < H; ++k) o = fmaf(r1[k], Wr2[k * NCLS + j], o);
        out[g * NCLS + j] = o;
    }
}

// ---------------------------------------------------------------------------
extern "C" void kernel_launch(void* const* d_in, const int* in_sizes, int n_in,
                              void* d_out, int out_size, void* d_ws, size_t ws_size,
                              hipStream_t stream)
{
    const float* x       = (const float*)d_in[0];
    const float* pe      = (const float*)d_in[1];
    const int*   ei      = (const int*)d_in[2];
    const float* ea      = (const float*)d_in[3];
    const int*   batch   = (const int*)d_in[4];
    const float* W_in    = (const float*)d_in[5];
    const float* b_in    = (const float*)d_in[6];
    const float* We_edge = (const float*)d_in[7];
    const float* be_edge = (const float*)d_in[8];
    const float* eps     = (const float*)d_in[9];
    const float* W1g     = (const float*)d_in[10];
    const float* b1g     = (const float*)d_in[11];
    const float* W2g     = (const float*)d_in[12];
    const float* b2g     = (const float*)d_in[13];
    const float* bn1g    = (const float*)d_in[14];
    const float* bn1b    = (const float*)d_in[15];
    const float* W1f     = (const float*)d_in[16];
    const float* b1f     = (const float*)d_in[17];
    const float* W2f     = (const float*)d_in[18];
    const float* b2f     = (const float*)d_in[19];
    const float* bn2g    = (const float*)d_in[20];
    const float* bn2b    = (const float*)d_in[21];
    const float* Wr1     = (const float*)d_in[22];
    const float* br1     = (const float*)d_in[23];
    const float* Wr2     = (const float*)d_in[24];
    const float* br2     = (const float*)d_in[25];
    float* out = (float*)d_out;

    const size_t NH = (size_t)NN * H;
    float* hbuf  = (float*)d_ws;                     // [NN,H] fp32
    float* tbuf  = hbuf + NH;                        // [NN,H] fp32 (t / u, in-place)
    unsigned short* zb = (unsigned short*)(tbuf + NH);  // [NN,H] bf16 z
    int*   perm  = (int*)(zb + NH);                  // [NE]
    // contiguous zero block: [deg NN][stats 16384][pool NG*H][cnt NG]
    int*   deg   = perm + NE;
    float* stats = (float*)(deg + NN);               // 4 layers x 2 slabs x 2048
    float* pool  = stats + 16384;                    // [NG,H]
    float* cnt   = pool + NG * H;                    // [NG]
    int*   rowptr = (int*)(cnt + NG);                // [NN+1]
    int*   cursor = rowptr + NN + 1;                 // [NN]
    int*   bsum   = cursor + NN;                     // [256]
    int*   src_s  = bsum + 256;                      // [NE]
    float* ea_s   = (float*)(src_s + NE);            // [NE,16]
    unsigned short* hb = (unsigned short*)(ea_s + (size_t)NE * 16);  // [NN,H] bf16
    unsigned short* wt = hb + NH;                    // 16 matrices x 2*K*N
    unsigned short* wt1g = wt;
    unsigned short* wt2g = wt + 4 * 65536;
    unsigned short* wt1f = wt + 8 * 65536;
    unsigned short* wt2f = wt + 12 * 65536;

    const dim3 blk(256);
    const dim3 ip_g((NN + 127) / 128, 1);
    const dim3 gp_g((NN + 127) / 128, 1);            // 391 blocks, BM=128
    const int ew_grid = (int)(NH / 256);
    const float inv_n = 1.0f / (float)NN;
    const size_t zero_bytes = (size_t)(NN + 16384 + NG * H + NG) * 4;

    // ---- weight prep ----
    wprep_all<<<2048, blk, 0, stream>>>(W1g, W2g, W1f, W2f, wt);

    // ---- zero-init + CSR build ----
    hipMemsetAsync(deg, 0, zero_bytes, stream);
    hist_kernel<<<(NE + 255) / 256, blk, 0, stream>>>(ei, deg);
    bsum_kernel<<<NB, blk, 0, stream>>>(deg, bsum);
    bscan_kernel<<<1, blk, 0, stream>>>(bsum);
    bwrite_kernel<<<NB, blk, 0, stream>>>(deg, bsum, rowptr, cursor);
    scat_idx<<<(NE + 255) / 256, blk, 0, stream>>>(ei, cursor, src_s, perm);
    gather_ea<<<(NE * 4) / 256, blk, 0, stream>>>(ea, perm, ea_s);

    // ---- input projection ----
    inproj_kernel<<<ip_g, blk, 0, stream>>>(x, pe, W_in, b_in, hbuf, hb, NN);

    for (int l = 0; l < 4; ++l) {
        float* s1 = stats + (size_t)l * 4096;
        float* s2 = s1 + 2048;

        // z (bf16) = (1+eps)*h + sum relu(h[src] + elin)
        agg_kernel<<<(NN + 3) / 4, blk, 0, stream>>>(hbuf, hb, rowptr, src_s, ea_s,
                                                     We_edge + (size_t)l * 16 * H,
                                                     be_edge + (size_t)l * H, eps, l, zb);

        // GIN pair: t = relu(z@W1g+b1g)@W2g + b2g   (+stats s1)
        gemm_pair<false><<<gp_g, blk, 0, stream>>>(
            zb, nullptr, wt1g + (size_t)l * 65536, wt2g + (size_t)l * 65536,
            b1g + (size_t)l * H2, b2g + (size_t)l * H,
            nullptr, nullptr, nullptr, s1, tbuf, inv_n, NN);

        // FFN pair: z = relu(bn1(t))+h; u = relu(z@W1f+b1f)@W2f + b2f + z  (+stats s2)
        gemm_pair<true><<<gp_g, blk, 0, stream>>>(
            tbuf, hbuf, wt1f + (size_t)l * 65536, wt2f + (size_t)l * 65536,
            b1f + (size_t)l * H2, b2f + (size_t)l * H,
            s1, bn1g + (size_t)l * H, bn1b + (size_t)l * H, s2, tbuf, inv_n, NN);

        // h = bn2(u)
        bn_apply_kernel<<<ew_grid, blk, 0, stream>>>(tbuf, s2, bn2g + (size_t)l * H,
                                                     bn2b + (size_t)l * H, hbuf, hb, inv_n);
    }

    pool_kernel<<<(NN + 255) / 256, blk, 0, stream>>>(hbuf, batch, pool, cnt, NN);
    readout_kernel<<<NG, H, 0, stream>>>(pool, cnt, Wr1, br1, Wr2, br2, out);
}